// Round 3
// baseline (420.726 us; speedup 1.0000x reference)
//
#include <hip/hip_runtime.h>
#include <cstdint>

// CrossAttentionFusion: seq_len=1 cross-attention => softmax==1 => attention is
// identity on V. Whole net collapses to:
//   W1 = w_o1 @ wv1 ; b1 = w_o1 @ bv1 + b_o1   (wv1 = w_qkv1[2d:3d,:])
//   z  = [x_u @ W1^T + b1 , x_m @ W2^T + b2]   [B, 2d]
//   out = gelu( LN(z; g,b) @ w_proj^T + b_proj )
// LN folded into proj epilogue: h = rstd*(z.Wp'^T - mu*S) + C.
// R3: x fp32->bf16 conversion fused into gemm_z A-staging (no x_bf pass),
// distinct kernel names per launch for rocprof attribution.

#define DIM 1024
#define BROWS 16384

typedef __bf16 bf16x8 __attribute__((ext_vector_type(8)));
typedef ushort ushort8v __attribute__((ext_vector_type(8)));
typedef float f32x4 __attribute__((ext_vector_type(4)));

__device__ __forceinline__ ushort f2bf(float f) {
    uint32_t u = __builtin_bit_cast(uint32_t, f);
    u = (u + 0x7fffu + ((u >> 16) & 1u)) >> 16;
    return (ushort)u;
}

// global -> LDS direct copy, 16B per lane. LDS dest is wave-uniform base;
// HW writes lane i at base + i*16.
__device__ __forceinline__ void async_copy16(const void* gsrc, void* ldst) {
    __builtin_amdgcn_global_load_lds(
        (__attribute__((address_space(1))) void*)((uintptr_t)gsrc),
        (__attribute__((address_space(3))) void*)((uint32_t)(uintptr_t)ldst),
        16, 0, 0);
}

// ---------------- merged prep kernel ----------------
// block ranges:
//  [0, 1024)     : vecprep (j = b)
//  [1024, 4096)  : convert wo1,wo2, Wp=g*wproj -> bf16 (1.5M float4 items)
//  [4096, 6144)  : LDS-tiled transpose wv -> wvT bf16  (2048 32x32 tiles)
//  [6144, 6176)  : zero sumbuf/sqbuf (32768 floats)

__global__ __launch_bounds__(256) void prep_kernel(
        const float* __restrict__ wqkv1, const float* __restrict__ bqkv1,
        const float* __restrict__ wo1, const float* __restrict__ bo1,
        const float* __restrict__ wqkv2, const float* __restrict__ bqkv2,
        const float* __restrict__ wo2, const float* __restrict__ bo2,
        const float* __restrict__ lng, const float* __restrict__ lnb,
        const float* __restrict__ wproj, const float* __restrict__ bproj,
        ushort* __restrict__ wo12, ushort* __restrict__ wvT12,
        ushort* __restrict__ Wp,
        float* __restrict__ b12, float* __restrict__ Svec, float* __restrict__ Cvec,
        float* __restrict__ sums /* sumbuf+sqbuf contiguous, 32768 floats */) {
    const int b = blockIdx.x, t = threadIdx.x;
    __shared__ float red[4][4];
    __shared__ float tls[32][33];

    if (b < 1024) {
        // ---- vecprep: b12[z*D+j], S[j], C[j] ----
        int j = b;
        float s1 = 0.f, s2 = 0.f, sS = 0.f, sC = 0.f;
        for (int c = t; c < DIM; c += 256) {
            s1 += wo1[j * DIM + c] * bqkv1[2 * DIM + c];
            s2 += wo2[j * DIM + c] * bqkv2[2 * DIM + c];
        }
        for (int c = t; c < 2 * DIM; c += 256) {
            float w = wproj[j * 2 * DIM + c];
            sS += w * lng[c];
            sC += w * lnb[c];
        }
        for (int o = 32; o; o >>= 1) {
            s1 += __shfl_down(s1, o, 64);
            s2 += __shfl_down(s2, o, 64);
            sS += __shfl_down(sS, o, 64);
            sC += __shfl_down(sC, o, 64);
        }
        int wid = t >> 6;
        if ((t & 63) == 0) { red[wid][0] = s1; red[wid][1] = s2; red[wid][2] = sS; red[wid][3] = sC; }
        __syncthreads();
        if (t == 0) {
            s1 = red[0][0] + red[1][0] + red[2][0] + red[3][0];
            s2 = red[0][1] + red[1][1] + red[2][1] + red[3][1];
            sS = red[0][2] + red[1][2] + red[2][2] + red[3][2];
            sC = red[0][3] + red[1][3] + red[2][3] + red[3][3];
            b12[j]       = s1 + bo1[j];
            b12[DIM + j] = s2 + bo2[j];
            Svec[j] = sS;
            Cvec[j] = sC + bproj[j];
        }
    } else if (b < 4096) {
        // ---- convert weights ----
        const int NWO = (DIM * DIM) / 4;
        const int NWP = (DIM * 2 * DIM) / 4;
        const int total = 2 * NWO + NWP;
        int i = (b - 1024) * 256 + t;
        const int stride = 3072 * 256;
        for (; i < total; i += stride) {
            if (i < 2 * NWO) {
                float4 v = (i < NWO) ? ((const float4*)wo1)[i] : ((const float4*)wo2)[i - NWO];
                ushort4 o;
                o.x = f2bf(v.x); o.y = f2bf(v.y); o.z = f2bf(v.z); o.w = f2bf(v.w);
                ((ushort4*)wo12)[i] = o;
            } else {
                int j = i - 2 * NWO;
                float4 v = ((const float4*)wproj)[j];
                int c = (j * 4) & (2 * DIM - 1);
                v.x *= lng[c]; v.y *= lng[c + 1]; v.z *= lng[c + 2]; v.w *= lng[c + 3];
                ushort4 o;
                o.x = f2bf(v.x); o.y = f2bf(v.y); o.z = f2bf(v.z); o.w = f2bf(v.w);
                ((ushort4*)Wp)[j] = o;
            }
        }
    } else if (b < 6144) {
        // ---- transpose wv -> wvT (bf16), 32x32 fp32 tiles via LDS ----
        int tile = b - 4096;
        int z = tile >> 10;
        int t2 = tile & 1023;
        int mt = t2 >> 5, kt = t2 & 31;
        const float* src = z ? wqkv2 : wqkv1;
        int tr = t >> 3;            // 0..31
        int tc4 = (t & 7) * 4;      // 0..28 step 4
        const float* p = src + (long)(2 * DIM + mt * 32 + tr) * DIM + kt * 32 + tc4;
        float4 v = *(const float4*)p;
        tls[tr][tc4 + 0] = v.x; tls[tr][tc4 + 1] = v.y;
        tls[tr][tc4 + 2] = v.z; tls[tr][tc4 + 3] = v.w;
        __syncthreads();
        ushort4 o;
        o.x = f2bf(tls[tc4 + 0][tr]);
        o.y = f2bf(tls[tc4 + 1][tr]);
        o.z = f2bf(tls[tc4 + 2][tr]);
        o.w = f2bf(tls[tc4 + 3][tr]);
        *(ushort4*)(wvT12 + (long)z * DIM * DIM + (long)(kt * 32 + tr) * DIM + mt * 32 + tc4) = o;
    } else {
        // ---- zero sums ----
        int i = (b - 6144) * 256 + t;   // 8192 float4
        ((float4*)sums)[i] = float4{0.f, 0.f, 0.f, 0.f};
    }
}

// ---------------- gemm_wfuse: W12[z] = wo12[z] @ wvT12[z]^T, 64x64 tile ----------------
__global__ __launch_bounds__(256, 2) void gemm_wfuse(
        const ushort* __restrict__ Ag, const ushort* __restrict__ Wg,
        ushort* __restrict__ Cg) {
    constexpr int BM = 64, BN = 64, BK = 32;
    constexpr int MT = 2, NT = 2;
    __shared__ __align__(16) ushort As[BM * BK];
    __shared__ __align__(16) ushort Bs[BN * BK];
    const int tid = threadIdx.x;
    const int wid = tid >> 6;
    const int lane = tid & 63;
    const int quad = lane >> 4;
    const int l16 = lane & 15;
    const int waveM = wid >> 1, waveN = wid & 1;
    const int zb = blockIdx.z;

    const ushort* A = Ag + (long)zb * DIM * DIM + (long)blockIdx.x * BM * DIM;
    const ushort* W = Wg + (long)zb * DIM * DIM + (long)blockIdx.y * BN * DIM;

    f32x4 acc[MT][NT] = {};
    const int rdA = quad ^ ((l16 >> 1) & 3);

    for (int k0 = 0; k0 < DIM; k0 += BK) {
        {
            int idx = tid;
            int r = idx >> 2;
            int q = (idx & 3) ^ ((r >> 1) & 3);
            async_copy16(A + (long)r * DIM + k0 + q * 8, (char*)As + (wid * 64) * 16);
            async_copy16(W + (long)r * DIM + k0 + q * 8, (char*)Bs + (wid * 64) * 16);
        }
        asm volatile("s_waitcnt vmcnt(0)" ::: "memory");
        __syncthreads();

        bf16x8 af[MT], bfg[NT];
#pragma unroll
        for (int im = 0; im < MT; im++)
            af[im] = *(const bf16x8*)(As + (waveM * 32 + im * 16 + l16) * BK + rdA * 8);
#pragma unroll
        for (int in = 0; in < NT; in++)
            bfg[in] = *(const bf16x8*)(Bs + (waveN * 32 + in * 16 + l16) * BK + rdA * 8);
#pragma unroll
        for (int im = 0; im < MT; im++)
#pragma unroll
            for (int in = 0; in < NT; in++)
                acc[im][in] = __builtin_amdgcn_mfma_f32_16x16x32_bf16(
                    af[im], bfg[in], acc[im][in], 0, 0, 0);
        __syncthreads();
    }

    const int gRow0 = blockIdx.x * BM + waveM * 32 + quad * 4;
    const int gCol0 = blockIdx.y * BN + waveN * 32 + l16;
    ushort* C = Cg + (long)zb * DIM * DIM;
#pragma unroll
    for (int im = 0; im < MT; im++)
#pragma unroll
        for (int in = 0; in < NT; in++) {
            int col = gCol0 + in * 16;
#pragma unroll
            for (int r = 0; r < 4; r++)
                C[(long)(gRow0 + im * 16 + r) * DIM + col] = f2bf(acc[im][in][r]);
        }
}

// ---------------- gemm_z: z[:, zb*D:(zb+1)*D] = x_zb @ W12[zb]^T + b12[zb] ----------------
// A is fp32 (raw x input); converted to bf16 in-register during staging.
// Fused LN-stats atomics into sumbuf/sqbuf.
__global__ __launch_bounds__(256, 2) void gemm_z(
        const float* __restrict__ x_u, const float* __restrict__ x_m,
        const ushort* __restrict__ Wg, ushort* __restrict__ Cg,
        const float* __restrict__ bias,
        float* __restrict__ sumbuf, float* __restrict__ sqbuf) {
    constexpr int BM = 128, BN = 128, BK = 32;
    constexpr int MT = 4, NT = 4;
    __shared__ __align__(16) ushort As[BM * BK];
    __shared__ __align__(16) ushort Bs[BN * BK];
    const int tid = threadIdx.x;
    const int wid = tid >> 6;
    const int lane = tid & 63;
    const int quad = lane >> 4;
    const int l16 = lane & 15;
    const int waveM = wid >> 1, waveN = wid & 1;
    const int zb = blockIdx.z;

    const float* A = (zb ? x_m : x_u) + (long)blockIdx.x * BM * DIM;
    const ushort* W = Wg + (long)zb * DIM * DIM + (long)blockIdx.y * BN * DIM;

    f32x4 acc[MT][NT] = {};
    const int rdA = quad ^ ((l16 >> 1) & 3);

    // A staging geometry: thread covers row ar = tid>>1, 16 floats at col half*16
    const int ar = tid >> 1;
    const int ahalf = tid & 1;
    const float* arow = A + (long)ar * DIM + ahalf * 16;
    // two bf16x8 chunks -> swizzled slots
    const int aswz = (ar >> 1) & 3;
    ushort* as0 = As + (ar * 4 + ((ahalf * 2 + 0) ^ aswz)) * 8;
    ushort* as1 = As + (ar * 4 + ((ahalf * 2 + 1) ^ aswz)) * 8;

    for (int k0 = 0; k0 < DIM; k0 += BK) {
        // B: async global->LDS (bf16 weights)
#pragma unroll
        for (int c = 0; c < 2; c++) {
            int idx = c * 256 + tid;
            int r = idx >> 2;
            int q = (idx & 3) ^ ((r >> 1) & 3);
            async_copy16(W + (long)r * DIM + k0 + q * 8,
                         (char*)Bs + (c * 256 + wid * 64) * 16);
        }
        // A: fp32 loads -> convert -> ds_write (swizzled)
        float4 v0 = *(const float4*)(arow + k0 + 0);
        float4 v1 = *(const float4*)(arow + k0 + 4);
        float4 v2 = *(const float4*)(arow + k0 + 8);
        float4 v3 = *(const float4*)(arow + k0 + 12);
        ushort8v c0, c1;
        c0[0] = f2bf(v0.x); c0[1] = f2bf(v0.y); c0[2] = f2bf(v0.z); c0[3] = f2bf(v0.w);
        c0[4] = f2bf(v1.x); c0[5] = f2bf(v1.y); c0[6] = f2bf(v1.z); c0[7] = f2bf(v1.w);
        c1[0] = f2bf(v2.x); c1[1] = f2bf(v2.y); c1[2] = f2bf(v2.z); c1[3] = f2bf(v2.w);
        c1[4] = f2bf(v3.x); c1[5] = f2bf(v3.y); c1[6] = f2bf(v3.z); c1[7] = f2bf(v3.w);
        *(ushort8v*)as0 = c0;
        *(ushort8v*)as1 = c1;
        asm volatile("s_waitcnt vmcnt(0)" ::: "memory");
        __syncthreads();

        bf16x8 af[MT], bfg[NT];
#pragma unroll
        for (int im = 0; im < MT; im++)
            af[im] = *(const bf16x8*)(As + (waveM * 64 + im * 16 + l16) * BK + rdA * 8);
#pragma unroll
        for (int in = 0; in < NT; in++)
            bfg[in] = *(const bf16x8*)(Bs + (waveN * 64 + in * 16 + l16) * BK + rdA * 8);
#pragma unroll
        for (int im = 0; im < MT; im++)
#pragma unroll
            for (int in = 0; in < NT; in++)
                acc[im][in] = __builtin_amdgcn_mfma_f32_16x16x32_bf16(
                    af[im], bfg[in], acc[im][in], 0, 0, 0);
        __syncthreads();
    }

    const int gRow0 = blockIdx.x * BM + waveM * 64 + quad * 4;
    const int gCol0 = blockIdx.y * BN + waveN * 64 + l16;
    ushort* C = Cg + (long)zb * DIM;   // column offset into [B, 2D]
    float rs[MT][4] = {};
    float rq[MT][4] = {};
#pragma unroll
    for (int im = 0; im < MT; im++)
#pragma unroll
        for (int in = 0; in < NT; in++) {
            int col = gCol0 + in * 16;
            float badd = bias[zb * DIM + col];
#pragma unroll
            for (int r = 0; r < 4; r++) {
                int row = gRow0 + im * 16 + r;
                float val = acc[im][in][r] + badd;
                C[(long)row * 2 * DIM + col] = f2bf(val);
                rs[im][r] += val;
                rq[im][r] += val * val;
            }
        }
#pragma unroll
    for (int im = 0; im < MT; im++)
#pragma unroll
        for (int r = 0; r < 4; r++) {
            float s = rs[im][r], q = rq[im][r];
#pragma unroll
            for (int o = 1; o < 16; o <<= 1) {
                s += __shfl_xor(s, o, 64);
                q += __shfl_xor(q, o, 64);
            }
            if (l16 == 0) {
                int row = gRow0 + im * 16 + r;
                atomicAdd(&sumbuf[row], s);
                atomicAdd(&sqbuf[row], q);
            }
        }
}

// ---------------- gemm_proj: out = gelu(rstd*(z @ Wp^T - mu*S) + C) ----------------
__global__ __launch_bounds__(256, 2) void gemm_proj(
        const ushort* __restrict__ Ag, const ushort* __restrict__ Wg,
        float* __restrict__ Og,
        const float* __restrict__ Svec, const float* __restrict__ Cvec,
        const float* __restrict__ sumbuf, const float* __restrict__ sqbuf) {
    constexpr int BM = 128, BN = 128, BK = 32;
    constexpr int MT = 4, NT = 4;
    constexpr int K = 2 * DIM, LDA = 2 * DIM, LDW = 2 * DIM, LDC = DIM;
    __shared__ __align__(16) ushort As[BM * BK];
    __shared__ __align__(16) ushort Bs[BN * BK];
    const int tid = threadIdx.x;
    const int wid = tid >> 6;
    const int lane = tid & 63;
    const int quad = lane >> 4;
    const int l16 = lane & 15;
    const int waveM = wid >> 1, waveN = wid & 1;

    const ushort* A = Ag + (long)blockIdx.x * BM * LDA;
    const ushort* W = Wg + (long)blockIdx.y * BN * LDW;

    f32x4 acc[MT][NT] = {};
    const int rdA = quad ^ ((l16 >> 1) & 3);

    for (int k0 = 0; k0 < K; k0 += BK) {
#pragma unroll
        for (int c = 0; c < 2; c++) {
            int idx = c * 256 + tid;
            int r = idx >> 2;
            int q = (idx & 3) ^ ((r >> 1) & 3);
            async_copy16(A + (long)r * LDA + k0 + q * 8,
                         (char*)As + (c * 256 + wid * 64) * 16);
        }
#pragma unroll
        for (int c = 0; c < 2; c++) {
            int idx = c * 256 + tid;
            int r = idx >> 2;
            int q = (idx & 3) ^ ((r >> 1) & 3);
            async_copy16(W + (long)r * LDW + k0 + q * 8,
                         (char*)Bs + (c * 256 + wid * 64) * 16);
        }
        asm volatile("s_waitcnt vmcnt(0)" ::: "memory");
        __syncthreads();

        bf16x8 af[MT], bfg[NT];
#pragma unroll
        for (int im = 0; im < MT; im++)
            af[im] = *(const bf16x8*)(As + (waveM * 64 + im * 16 + l16) * BK + rdA * 8);
#pragma unroll
        for (int in = 0; in < NT; in++)
            bfg[in] = *(const bf16x8*)(Bs + (waveN * 64 + in * 16 + l16) * BK + rdA * 8);
#pragma unroll
        for (int im = 0; im < MT; im++)
#pragma unroll
            for (int in = 0; in < NT; in++)
                acc[im][in] = __builtin_amdgcn_mfma_f32_16x16x32_bf16(
                    af[im], bfg[in], acc[im][in], 0, 0, 0);
        __syncthreads();
    }

    const int gRow0 = blockIdx.x * BM + waveM * 64 + quad * 4;
    const int gCol0 = blockIdx.y * BN + waveN * 64 + l16;
#pragma unroll
    for (int im = 0; im < MT; im++)
#pragma unroll
        for (int r = 0; r < 4; r++) {
            int row = gRow0 + im * 16 + r;
            float sv = sumbuf[row], qv = sqbuf[row];
            float m = sv * (1.f / 2048.f);
            float var = qv * (1.f / 2048.f) - m * m;
            float rstd = rsqrtf(var + 1e-5f);
#pragma unroll
            for (int in = 0; in < NT; in++) {
                int col = gCol0 + in * 16;
                float h = rstd * (acc[im][in][r] - m * Svec[col]) + Cvec[col];
                Og[(long)row * LDC + col] = 0.5f * h * (1.0f + erff(h * 0.7071067811865475f));
            }
        }
}

// ---------------- launch ----------------

extern "C" void kernel_launch(void* const* d_in, const int* in_sizes, int n_in,
                              void* d_out, int out_size, void* d_ws, size_t ws_size,
                              hipStream_t stream) {
    (void)in_sizes; (void)n_in; (void)out_size; (void)ws_size;
    const float* x_u   = (const float*)d_in[0];
    const float* x_m   = (const float*)d_in[1];
    const float* wqkv1 = (const float*)d_in[2];
    const float* bqkv1 = (const float*)d_in[3];
    const float* wo1   = (const float*)d_in[4];
    const float* bo1   = (const float*)d_in[5];
    const float* wqkv2 = (const float*)d_in[6];
    const float* bqkv2 = (const float*)d_in[7];
    const float* wo2   = (const float*)d_in[8];
    const float* bo2   = (const float*)d_in[9];
    const float* lng   = (const float*)d_in[10];
    const float* lnb   = (const float*)d_in[11];
    const float* wproj = (const float*)d_in[12];
    const float* bproj = (const float*)d_in[13];

    char* ws = (char*)d_ws;
    ushort* wo12  = (ushort*)(ws + 0);          // [2][D][D]: 4 MB
    ushort* wvT12 = (ushort*)(ws + 4194304);    // [2][D][D]: 4 MB
    ushort* W12   = (ushort*)(ws + 8388608);    // [2][D][D]: 4 MB
    ushort* Wp    = (ushort*)(ws + 12582912);   // [D][2D]: 4 MB
    ushort* zbuf  = (ushort*)(ws + 16777216);   // [B][2D] bf16: 64 MB
    float*  b12   = (float*)(ws + 83886080);    // [2][D]
    float*  Svec  = (float*)(ws + 83894272);    // [D]
    float*  Cvec  = (float*)(ws + 83898368);    // [D]
    float*  sumbuf= (float*)(ws + 83902464);    // [B]
    float*  sqbuf = (float*)(ws + 83968000);    // [B]
    // total ws use: 84,033,536 B

    prep_kernel<<<6176, 256, 0, stream>>>(
        wqkv1, bqkv1, wo1, bo1, wqkv2, bqkv2, wo2, bo2,
        lng, lnb, wproj, bproj,
        wo12, wvT12, Wp, b12, Svec, Cvec, sumbuf);

    // W12[z] = wo12[z] @ wvT12[z]^T   (1024x1024, K=1024)
    gemm_wfuse<<<dim3(16, 16, 2), 256, 0, stream>>>(wo12, wvT12, W12);

    // z[:, z*D:(z+1)*D] = x_z @ W12[z]^T + b12[z]  (+ fused LN stats)
    gemm_z<<<dim3(128, 8, 2), 256, 0, stream>>>(
        x_u, x_m, W12, zbuf, b12, sumbuf, sqbuf);

    // out = gelu(rstd*(z @ Wp^T - mu*S) + C)
    gemm_proj<<<dim3(128, 8, 1), 256, 0, stream>>>(
        zbuf, Wp, (float*)d_out, Svec, Cvec, sumbuf, sqbuf);
}